// Round 1
// baseline (833.745 us; speedup 1.0000x reference)
//
#include <hip/hip_runtime.h>
#include <math.h>

typedef float f4 __attribute__((ext_vector_type(4)));

constexpr int kB = 64;
constexpr int kLs = 256;
constexpr int kM = 4;
constexpr int kLw = 256;
constexpr int kLy = 128;
constexpr int kHid = 512;
constexpr int kSteps = 6;
constexpr float kEps = 1e-5f;

__device__ __forceinline__ float wred(float v) {
#pragma unroll
  for (int off = 32; off > 0; off >>= 1) v += __shfl_down(v, off, 64);
  return v;
}

// h_static[b,m,hid] = b1[hid] + sum_l wy[b,m,l] * W1[512+l, hid]
// grid: 128 blocks (64 b x 2 hid-chunks of 256), 256 threads
__global__ __launch_bounds__(256) void k_static(
    const float* __restrict__ wr, const float* __restrict__ wi,
    const float* __restrict__ yy, const float* __restrict__ W1,
    const float* __restrict__ b1, float* __restrict__ hstat) {
  const int b = blockIdx.x >> 1;
  const int hid = ((blockIdx.x & 1) << 8) + threadIdx.x;
  const float* w1c = W1 + hid;
  f4 acc = {0.f, 0.f, 0.f, 0.f};
#pragma unroll 4
  for (int l = 0; l < kLw; ++l) {
    const float w1v = w1c[(size_t)(2 * kLs + l) * kHid];
    const f4 w = *(const f4*)(wr + ((size_t)b * kLw + l) * kM);
#pragma unroll
    for (int m = 0; m < kM; ++m) acc[m] += w[m] * w1v;
  }
#pragma unroll 4
  for (int l = 0; l < kLw; ++l) {
    const float w1v = w1c[(size_t)(2 * kLs + kLw + l) * kHid];
    const f4 w = *(const f4*)(wi + ((size_t)b * kLw + l) * kM);
#pragma unroll
    for (int m = 0; m < kM; ++m) acc[m] += w[m] * w1v;
  }
#pragma unroll 4
  for (int l = 0; l < kLy; ++l) {
    const float w1v = w1c[(size_t)(2 * kLs + 2 * kLw + l) * kHid];
    const f4 w = *(const f4*)(yy + ((size_t)b * kLy + l) * kM);
#pragma unroll
    for (int m = 0; m < kM; ++m) acc[m] += w[m] * w1v;
  }
  const float bv = b1[hid];
#pragma unroll
  for (int m = 0; m < kM; ++m)
    hstat[((size_t)b * kM + m) * kHid + hid] = acc[m] + bv;
}

// Per-step heavy kernel.
// Blocks 0..4095: matvec. block -> (b = blk>>6, ic = blk&63); wave w handles
//   i = ic*4 + w.  Gs[b,i,m] = sum_j G[b,i,j,m]*s[b,j] (complex), same for H.
// Blocks 4096..4223: h_dyn[b,hid] = sum_j Re(s_j)*W1[j,hid] + Im(s_j)*W1[256+j,hid]
__global__ __launch_bounds__(256) void k_step_main(
    const float* __restrict__ Gr, const float* __restrict__ Gi,
    const float* __restrict__ Hr, const float* __restrict__ Hi,
    const float* __restrict__ W1, const float* __restrict__ phi,
    float* __restrict__ gsR, float* __restrict__ gsI,
    float* __restrict__ hsR, float* __restrict__ hsI,
    float* __restrict__ hdyn,
    float* __restrict__ outSR, float* __restrict__ outSI, int step) {
  __shared__ float sRe[kLs], sIm[kLs];
  const int t = threadIdx.x;
  const int blk = blockIdx.x;
  const int nMat = kB * kLs / 4;  // 4096
  const int b = (blk < nMat) ? (blk >> 6) : ((blk - nMat) >> 1);
  const float p = phi[b * kLs + t];
  float sn, cs;
  sincosf(p, &sn, &cs);
  sRe[t] = cs;
  sIm[t] = sn;
  __syncthreads();

  if (blk < nMat) {
    const int ic = blk & 63;
    if (ic == 0) {  // one block per b writes s outputs for this step
      const size_t oo = ((size_t)b * (kSteps + 1) + step) * kLs + t;
      outSR[oo] = cs;
      outSI[oo] = sn;
    }
    const int wv = t >> 6, lane = t & 63;
    const int i = (ic << 2) + wv;
    const size_t rowoff = ((size_t)b * kLs + i) * kLs * kM;
    const float* grp = Gr + rowoff;
    const float* gip = Gi + rowoff;
    const float* hrp = Hr + rowoff;
    const float* hip_ = Hi + rowoff;
    f4 aGr = {0, 0, 0, 0}, aGi = {0, 0, 0, 0};
    f4 aHr = {0, 0, 0, 0}, aHi = {0, 0, 0, 0};
#pragma unroll
    for (int r = 0; r < 4; ++r) {
      const int j = (r << 6) + lane;
      const f4 g_r = *(const f4*)(grp + (size_t)j * kM);
      const f4 g_i = *(const f4*)(gip + (size_t)j * kM);
      const f4 h_r = *(const f4*)(hrp + (size_t)j * kM);
      const f4 h_i = *(const f4*)(hip_ + (size_t)j * kM);
      const float sr = sRe[j], si = sIm[j];
#pragma unroll
      for (int m = 0; m < kM; ++m) {
        aGr[m] += g_r[m] * sr - g_i[m] * si;
        aGi[m] += g_r[m] * si + g_i[m] * sr;
        aHr[m] += h_r[m] * sr - h_i[m] * si;
        aHi[m] += h_r[m] * si + h_i[m] * sr;
      }
    }
#pragma unroll
    for (int m = 0; m < kM; ++m) {
      aGr[m] = wred(aGr[m]);
      aGi[m] = wred(aGi[m]);
      aHr[m] = wred(aHr[m]);
      aHi[m] = wred(aHi[m]);
    }
    if (lane == 0) {
      const size_t o = ((size_t)b * kLs + i) * kM;
      *(f4*)(gsR + o) = aGr;
      *(f4*)(gsI + o) = aGi;
      *(f4*)(hsR + o) = aHr;
      *(f4*)(hsI + o) = aHi;
    }
  } else {
    const int d = blk - nMat;
    const int hid = ((d & 1) << 8) + t;
    const float* w1c = W1 + hid;
    float acc = 0.f;
#pragma unroll 4
    for (int j = 0; j < kLs; ++j) {
      acc += sRe[j] * w1c[(size_t)j * kHid];
      acc += sIm[j] * w1c[(size_t)(j + kLs) * kHid];
    }
    hdyn[b * kHid + hid] = acc;
  }
}

// Per-step tail: one block per b. sGs/sHs, BN stats (redundant per block),
// rho, eta_net, phi update.
__global__ __launch_bounds__(256) void k_step_finish(
    const float* __restrict__ gsR, const float* __restrict__ gsI,
    const float* __restrict__ hsR, const float* __restrict__ hsI,
    const float* __restrict__ hdyn, const float* __restrict__ hstat,
    const float* __restrict__ gamma_, const float* __restrict__ beta_,
    const float* __restrict__ W2, const float* __restrict__ b2,
    float* __restrict__ phi, float* __restrict__ outRho, int step) {
  const int b = blockIdx.x, t = threadIdx.x;
  const int lane = t & 63, wv = t >> 6;
  __shared__ float red[4][16];
  __shared__ float sgR[4], sgI[4], shR[4], shI[4], c2[4];
  __shared__ float mu_s[kM * kHid];
  __shared__ float rs_s[kM * kHid];
  __shared__ float rho_s[4];

  const float p = phi[b * kLs + t];
  float sn, cs;
  sincosf(p, &sn, &cs);

  const size_t o = ((size_t)b * kLs + t) * kM;
  const f4 gR = *(const f4*)(gsR + o);
  const f4 gI = *(const f4*)(gsI + o);
  const f4 hR = *(const f4*)(hsR + o);
  const f4 hI = *(const f4*)(hsI + o);

  // partials of sGs = sum_i conj(s_i)*Gs[i], sHs likewise
  float v[16];
#pragma unroll
  for (int m = 0; m < kM; ++m) {
    v[m] = cs * gR[m] + sn * gI[m];       // Re(conj(s)*Gs)
    v[4 + m] = cs * gI[m] - sn * gR[m];   // Im(conj(s)*Gs)
    v[8 + m] = cs * hR[m] + sn * hI[m];
    v[12 + m] = cs * hI[m] - sn * hR[m];
  }
#pragma unroll
  for (int k = 0; k < 16; ++k) v[k] = wred(v[k]);
  if (lane == 0) {
#pragma unroll
    for (int k = 0; k < 16; ++k) red[wv][k] = v[k];
  }
  __syncthreads();
  if (t == 0) {
#pragma unroll
    for (int m = 0; m < kM; ++m) {
      const float gr = red[0][m] + red[1][m] + red[2][m] + red[3][m];
      const float gi = red[0][4 + m] + red[1][4 + m] + red[2][4 + m] + red[3][4 + m];
      const float hr = red[0][8 + m] + red[1][8 + m] + red[2][8 + m] + red[3][8 + m];
      const float hi = red[0][12 + m] + red[1][12 + m] + red[2][12 + m] + red[3][12 + m];
      sgR[m] = gr; sgI[m] = gi; shR[m] = hr; shI[m] = hi;
      const float xr = hr * hr - hi * hi;   // Re(sHs^2)
      const float xi = 2.f * hr * hi;       // Im(sHs^2)
      c2[m] = 2.f * xr / (xr * xr + xi * xi);  // Re(2/sHs^2)
    }
  }

  // BN batch stats over b for each (m,hid): 2048 pairs / 256 threads = 8 each
#pragma unroll
  for (int k = 0; k < 8; ++k) {
    const int q = k * 256 + t;
    const int m = q >> 9;
    const int hid = q & (kHid - 1);
    float sum = 0.f, ss = 0.f;
    for (int bb = 0; bb < kB; ++bb) {
      const float h = hdyn[bb * kHid + hid] + hstat[((size_t)bb * kM + m) * kHid + hid];
      sum += h;
      ss += h * h;
    }
    const float mu = sum * (1.f / kB);
    const float var = ss * (1.f / kB) - mu * mu;
    mu_s[q] = mu;
    rs_s[q] = rsqrtf(var + kEps);
  }
  __syncthreads();

  // rho[b,m] = sigmoid( relu(bn(h)) . W2 + b2 )
  float pm[4] = {0.f, 0.f, 0.f, 0.f};
#pragma unroll
  for (int kk = 0; kk < 2; ++kk) {
    const int hid = (kk << 8) + t;
    const float hd = hdyn[b * kHid + hid];
    const float ga = gamma_[hid], be = beta_[hid], w2 = W2[hid];
#pragma unroll
    for (int m = 0; m < kM; ++m) {
      const float h = hd + hstat[((size_t)b * kM + m) * kHid + hid];
      const int q = m * kHid + hid;
      float hn = ga * (h - mu_s[q]) * rs_s[q] + be;
      hn = fmaxf(hn, 0.f);
      pm[m] += hn * w2;
    }
  }
#pragma unroll
  for (int m = 0; m < kM; ++m) pm[m] = wred(pm[m]);
  __syncthreads();  // protect reuse of red[][]
  if (lane == 0) {
#pragma unroll
    for (int m = 0; m < kM; ++m) red[wv][m] = pm[m];
  }
  __syncthreads();
  if (t < 4) {
    const float tot = red[0][t] + red[1][t] + red[2][t] + red[3][t] + b2[0];
    const float r = 1.f / (1.f + expf(-tot));
    rho_s[t] = r;
    outRho[((size_t)b * kSteps + step) * kM + t] = r;
  }
  __syncthreads();

  // eta_net[b,i=t] = sum_m c2[m] * Im((sHs*Gs - sGs*Hs)*conj(s_i)) * rho[m]
  float en = 0.f;
#pragma unroll
  for (int m = 0; m < kM; ++m) {
    const float ar = shR[m] * gR[m] - shI[m] * gI[m] - (sgR[m] * hR[m] - sgI[m] * hI[m]);
    const float ai = shR[m] * gI[m] + shI[m] * gR[m] - (sgR[m] * hI[m] + sgI[m] * hR[m]);
    en += c2[m] * (ai * cs - ar * sn) * rho_s[m];
  }
  phi[b * kLs + t] = p - en;
}

__global__ __launch_bounds__(256) void k_final(const float* __restrict__ phi,
                                               float* __restrict__ outSR,
                                               float* __restrict__ outSI) {
  const int b = blockIdx.x, t = threadIdx.x;
  float sn, cs;
  sincosf(phi[b * kLs + t], &sn, &cs);
  const size_t oo = ((size_t)b * (kSteps + 1) + kSteps) * kLs + t;
  outSR[oo] = cs;
  outSI[oo] = sn;
}

extern "C" void kernel_launch(void* const* d_in, const int* in_sizes, int n_in,
                              void* d_out, int out_size, void* d_ws, size_t ws_size,
                              hipStream_t stream) {
  const float* phi_in = (const float*)d_in[0];
  const float* w_real = (const float*)d_in[1];
  const float* w_imag = (const float*)d_in[2];
  const float* y = (const float*)d_in[3];
  const float* G_real = (const float*)d_in[4];
  const float* G_imag = (const float*)d_in[5];
  const float* H_real = (const float*)d_in[6];
  const float* H_imag = (const float*)d_in[7];
  const float* W1 = (const float*)d_in[8];
  const float* b1 = (const float*)d_in[9];
  const float* gamma_ = (const float*)d_in[10];
  const float* beta_ = (const float*)d_in[11];
  const float* W2 = (const float*)d_in[12];
  const float* b2 = (const float*)d_in[13];

  float* ws = (float*)d_ws;
  float* phi = ws;                    // 16384
  float* gsR = phi + kB * kLs;        // 65536 each
  float* gsI = gsR + kB * kLs * kM;
  float* hsR = gsI + kB * kLs * kM;
  float* hsI = hsR + kB * kLs * kM;
  float* hdyn = hsI + kB * kLs * kM;  // 32768
  float* hstat = hdyn + kB * kHid;    // 131072

  float* out = (float*)d_out;
  float* outSR = out;
  float* outSI = out + (size_t)kB * (kSteps + 1) * kLs;
  float* outRho = out + 2 * (size_t)kB * (kSteps + 1) * kLs;

  hipMemcpyAsync(phi, phi_in, (size_t)kB * kLs * sizeof(float),
                 hipMemcpyDeviceToDevice, stream);
  k_static<<<dim3(kB * 2), dim3(256), 0, stream>>>(w_real, w_imag, y, W1, b1, hstat);
  for (int step = 0; step < kSteps; ++step) {
    k_step_main<<<dim3(kB * kLs / 4 + kB * 2), dim3(256), 0, stream>>>(
        G_real, G_imag, H_real, H_imag, W1, phi, gsR, gsI, hsR, hsI, hdyn,
        outSR, outSI, step);
    k_step_finish<<<dim3(kB), dim3(256), 0, stream>>>(
        gsR, gsI, hsR, hsI, hdyn, hstat, gamma_, beta_, W2, b2, phi, outRho, step);
  }
  k_final<<<dim3(kB), dim3(256), 0, stream>>>(phi, outSR, outSI);
}

// Round 2
// 715.314 us; speedup vs baseline: 1.1656x; 1.1656x over previous
//
#include <hip/hip_runtime.h>
#include <math.h>

typedef float f4 __attribute__((ext_vector_type(4)));

constexpr int kB = 64;
constexpr int kLs = 256;
constexpr int kM = 4;
constexpr int kLw = 256;
constexpr int kLy = 128;
constexpr int kHid = 512;
constexpr int kSteps = 6;
constexpr float kEps = 1e-5f;

__device__ __forceinline__ float wred(float v) {
#pragma unroll
  for (int off = 32; off > 0; off >>= 1) v += __shfl_down(v, off, 64);
  return v;
}

// h_static[b,m,hid] = b1[hid] + sum_l wy[b,m,l] * W1[512+l, hid]
__global__ __launch_bounds__(256) void k_static(
    const float* __restrict__ wr, const float* __restrict__ wi,
    const float* __restrict__ yy, const float* __restrict__ W1,
    const float* __restrict__ b1, float* __restrict__ hstat) {
  const int b = blockIdx.x >> 1;
  const int hid = ((blockIdx.x & 1) << 8) + threadIdx.x;
  const float* w1c = W1 + hid;
  f4 acc = {0.f, 0.f, 0.f, 0.f};
#pragma unroll 4
  for (int l = 0; l < kLw; ++l) {
    const float w1v = w1c[(size_t)(2 * kLs + l) * kHid];
    const f4 w = *(const f4*)(wr + ((size_t)b * kLw + l) * kM);
#pragma unroll
    for (int m = 0; m < kM; ++m) acc[m] += w[m] * w1v;
  }
#pragma unroll 4
  for (int l = 0; l < kLw; ++l) {
    const float w1v = w1c[(size_t)(2 * kLs + kLw + l) * kHid];
    const f4 w = *(const f4*)(wi + ((size_t)b * kLw + l) * kM);
#pragma unroll
    for (int m = 0; m < kM; ++m) acc[m] += w[m] * w1v;
  }
#pragma unroll 4
  for (int l = 0; l < kLy; ++l) {
    const float w1v = w1c[(size_t)(2 * kLs + 2 * kLw + l) * kHid];
    const f4 w = *(const f4*)(yy + ((size_t)b * kLy + l) * kM);
#pragma unroll
    for (int m = 0; m < kM; ++m) acc[m] += w[m] * w1v;
  }
  const float bv = b1[hid];
#pragma unroll
  for (int m = 0; m < kM; ++m)
    hstat[((size_t)b * kM + m) * kHid + hid] = acc[m] + bv;
}

// Per-step heavy kernel.
// Blocks 0..4095: matvec, one wave per (b,i) row; LOAD-ALL-THEN-COMPUTE so all
//   16 dwordx4 loads (256 B/lane) are in flight before the first FMA wait.
// Blocks 4096..4223: h_dyn[b,hid].
__global__ __launch_bounds__(256) void k_step_main(
    const float* __restrict__ Gr, const float* __restrict__ Gi,
    const float* __restrict__ Hr, const float* __restrict__ Hi,
    const float* __restrict__ W1, const float* __restrict__ phi,
    float* __restrict__ gsR, float* __restrict__ gsI,
    float* __restrict__ hsR, float* __restrict__ hsI,
    float* __restrict__ hdyn,
    float* __restrict__ outSR, float* __restrict__ outSI, int step) {
  __shared__ float sRe[kLs], sIm[kLs];
  const int t = threadIdx.x;
  const int blk = blockIdx.x;
  const int nMat = kB * kLs / 4;  // 4096
  const int b = (blk < nMat) ? (blk >> 6) : ((blk - nMat) >> 1);
  const float p = phi[b * kLs + t];
  float sn, cs;
  sincosf(p, &sn, &cs);
  sRe[t] = cs;
  sIm[t] = sn;
  __syncthreads();

  if (blk < nMat) {
    const int ic = blk & 63;
    if (ic == 0) {  // one block per b writes s outputs for this step
      const size_t oo = ((size_t)b * (kSteps + 1) + step) * kLs + t;
      outSR[oo] = cs;
      outSI[oo] = sn;
    }
    const int wv = t >> 6, lane = t & 63;
    const int i = (ic << 2) + wv;
    const size_t rowoff = ((size_t)b * kLs + i) * kLs * kM;
    const float* grp = Gr + rowoff + (size_t)lane * kM;
    const float* gip = Gi + rowoff + (size_t)lane * kM;
    const float* hrp = Hr + rowoff + (size_t)lane * kM;
    const float* hip_ = Hi + rowoff + (size_t)lane * kM;

    // ---- issue ALL 16 16-byte loads before any use ----
    f4 g_r[4], g_i[4], h_r[4], h_i[4];
#pragma unroll
    for (int r = 0; r < 4; ++r) {
      const size_t off = (size_t)(r << 6) * kM;
      g_r[r] = *(const f4*)(grp + off);
      g_i[r] = *(const f4*)(gip + off);
      h_r[r] = *(const f4*)(hrp + off);
      h_i[r] = *(const f4*)(hip_ + off);
    }

    f4 aGr = {0, 0, 0, 0}, aGi = {0, 0, 0, 0};
    f4 aHr = {0, 0, 0, 0}, aHi = {0, 0, 0, 0};
#pragma unroll
    for (int r = 0; r < 4; ++r) {
      const int j = (r << 6) + lane;
      const float sr = sRe[j], si = sIm[j];
#pragma unroll
      for (int m = 0; m < kM; ++m) {
        aGr[m] += g_r[r][m] * sr - g_i[r][m] * si;
        aGi[m] += g_r[r][m] * si + g_i[r][m] * sr;
        aHr[m] += h_r[r][m] * sr - h_i[r][m] * si;
        aHi[m] += h_r[r][m] * si + h_i[r][m] * sr;
      }
    }
#pragma unroll
    for (int m = 0; m < kM; ++m) {
      aGr[m] = wred(aGr[m]);
      aGi[m] = wred(aGi[m]);
      aHr[m] = wred(aHr[m]);
      aHi[m] = wred(aHi[m]);
    }
    if (lane == 0) {
      const size_t o = ((size_t)b * kLs + i) * kM;
      *(f4*)(gsR + o) = aGr;
      *(f4*)(gsI + o) = aGi;
      *(f4*)(hsR + o) = aHr;
      *(f4*)(hsI + o) = aHi;
    }
  } else {
    const int d = blk - nMat;
    const int hid = ((d & 1) << 8) + t;
    const float* w1c = W1 + hid;
    float acc = 0.f;
#pragma unroll 4
    for (int j = 0; j < kLs; ++j) {
      acc += sRe[j] * w1c[(size_t)j * kHid];
      acc += sIm[j] * w1c[(size_t)(j + kLs) * kHid];
    }
    hdyn[b * kHid + hid] = acc;
  }
}

// BN batch stats over b for each (m,hid). grid: 8 blocks x 256 threads.
__global__ __launch_bounds__(256) void k_bn(
    const float* __restrict__ hdyn, const float* __restrict__ hstat,
    float* __restrict__ mu_g, float* __restrict__ rs_g) {
  const int q = blockIdx.x * 256 + threadIdx.x;  // 0..2047
  const int m = q >> 9;
  const int hid = q & (kHid - 1);
  float sum = 0.f, ss = 0.f;
#pragma unroll 8
  for (int bb = 0; bb < kB; ++bb) {
    const float h = hdyn[bb * kHid + hid] + hstat[((size_t)bb * kM + m) * kHid + hid];
    sum += h;
    ss += h * h;
  }
  const float mu = sum * (1.f / kB);
  const float var = ss * (1.f / kB) - mu * mu;
  mu_g[q] = mu;
  rs_g[q] = rsqrtf(var + kEps);
}

// Per-step tail: one block per b. sGs/sHs, rho, eta_net, phi update.
__global__ __launch_bounds__(256) void k_step_finish(
    const float* __restrict__ gsR, const float* __restrict__ gsI,
    const float* __restrict__ hsR, const float* __restrict__ hsI,
    const float* __restrict__ hdyn, const float* __restrict__ hstat,
    const float* __restrict__ mu_g, const float* __restrict__ rs_g,
    const float* __restrict__ gamma_, const float* __restrict__ beta_,
    const float* __restrict__ W2, const float* __restrict__ b2,
    float* __restrict__ phi, float* __restrict__ outRho, int step) {
  const int b = blockIdx.x, t = threadIdx.x;
  const int lane = t & 63, wv = t >> 6;
  __shared__ float red[4][16];
  __shared__ float sgR[4], sgI[4], shR[4], shI[4], c2[4];
  __shared__ float rho_s[4];

  const float p = phi[b * kLs + t];
  float sn, cs;
  sincosf(p, &sn, &cs);

  const size_t o = ((size_t)b * kLs + t) * kM;
  const f4 gR = *(const f4*)(gsR + o);
  const f4 gI = *(const f4*)(gsI + o);
  const f4 hR = *(const f4*)(hsR + o);
  const f4 hI = *(const f4*)(hsI + o);

  // partials of sGs = sum_i conj(s_i)*Gs[i], sHs likewise
  float v[16];
#pragma unroll
  for (int m = 0; m < kM; ++m) {
    v[m] = cs * gR[m] + sn * gI[m];       // Re(conj(s)*Gs)
    v[4 + m] = cs * gI[m] - sn * gR[m];   // Im(conj(s)*Gs)
    v[8 + m] = cs * hR[m] + sn * hI[m];
    v[12 + m] = cs * hI[m] - sn * hR[m];
  }
#pragma unroll
  for (int k = 0; k < 16; ++k) v[k] = wred(v[k]);
  if (lane == 0) {
#pragma unroll
    for (int k = 0; k < 16; ++k) red[wv][k] = v[k];
  }
  __syncthreads();
  if (t == 0) {
#pragma unroll
    for (int m = 0; m < kM; ++m) {
      const float gr = red[0][m] + red[1][m] + red[2][m] + red[3][m];
      const float gi = red[0][4 + m] + red[1][4 + m] + red[2][4 + m] + red[3][4 + m];
      const float hr = red[0][8 + m] + red[1][8 + m] + red[2][8 + m] + red[3][8 + m];
      const float hi = red[0][12 + m] + red[1][12 + m] + red[2][12 + m] + red[3][12 + m];
      sgR[m] = gr; sgI[m] = gi; shR[m] = hr; shI[m] = hi;
      const float xr = hr * hr - hi * hi;   // Re(sHs^2)
      const float xi = 2.f * hr * hi;       // Im(sHs^2)
      c2[m] = 2.f * xr / (xr * xr + xi * xi);  // Re(2/sHs^2)
    }
  }
  __syncthreads();

  // rho[b,m] = sigmoid( relu(bn(h)) . W2 + b2 )
  float pm[4] = {0.f, 0.f, 0.f, 0.f};
#pragma unroll
  for (int kk = 0; kk < 2; ++kk) {
    const int hid = (kk << 8) + t;
    const float hd = hdyn[b * kHid + hid];
    const float ga = gamma_[hid], be = beta_[hid], w2 = W2[hid];
#pragma unroll
    for (int m = 0; m < kM; ++m) {
      const float h = hd + hstat[((size_t)b * kM + m) * kHid + hid];
      const int q = m * kHid + hid;
      float hn = ga * (h - mu_g[q]) * rs_g[q] + be;
      hn = fmaxf(hn, 0.f);
      pm[m] += hn * w2;
    }
  }
#pragma unroll
  for (int m = 0; m < kM; ++m) pm[m] = wred(pm[m]);
  if (lane == 0) {
#pragma unroll
    for (int m = 0; m < kM; ++m) red[wv][m] = pm[m];
  }
  __syncthreads();
  if (t < 4) {
    const float tot = red[0][t] + red[1][t] + red[2][t] + red[3][t] + b2[0];
    const float r = 1.f / (1.f + expf(-tot));
    rho_s[t] = r;
    outRho[((size_t)b * kSteps + step) * kM + t] = r;
  }
  __syncthreads();

  // eta_net[b,i=t] = sum_m c2[m] * Im((sHs*Gs - sGs*Hs)*conj(s_i)) * rho[m]
  float en = 0.f;
#pragma unroll
  for (int m = 0; m < kM; ++m) {
    const float ar = shR[m] * gR[m] - shI[m] * gI[m] - (sgR[m] * hR[m] - sgI[m] * hI[m]);
    const float ai = shR[m] * gI[m] + shI[m] * gR[m] - (sgR[m] * hI[m] + sgI[m] * hR[m]);
    en += c2[m] * (ai * cs - ar * sn) * rho_s[m];
  }
  phi[b * kLs + t] = p - en;
}

__global__ __launch_bounds__(256) void k_final(const float* __restrict__ phi,
                                               float* __restrict__ outSR,
                                               float* __restrict__ outSI) {
  const int b = blockIdx.x, t = threadIdx.x;
  float sn, cs;
  sincosf(phi[b * kLs + t], &sn, &cs);
  const size_t oo = ((size_t)b * (kSteps + 1) + kSteps) * kLs + t;
  outSR[oo] = cs;
  outSI[oo] = sn;
}

extern "C" void kernel_launch(void* const* d_in, const int* in_sizes, int n_in,
                              void* d_out, int out_size, void* d_ws, size_t ws_size,
                              hipStream_t stream) {
  const float* phi_in = (const float*)d_in[0];
  const float* w_real = (const float*)d_in[1];
  const float* w_imag = (const float*)d_in[2];
  const float* y = (const float*)d_in[3];
  const float* G_real = (const float*)d_in[4];
  const float* G_imag = (const float*)d_in[5];
  const float* H_real = (const float*)d_in[6];
  const float* H_imag = (const float*)d_in[7];
  const float* W1 = (const float*)d_in[8];
  const float* b1 = (const float*)d_in[9];
  const float* gamma_ = (const float*)d_in[10];
  const float* beta_ = (const float*)d_in[11];
  const float* W2 = (const float*)d_in[12];
  const float* b2 = (const float*)d_in[13];

  float* ws = (float*)d_ws;
  float* phi = ws;                    // 16384
  float* gsR = phi + kB * kLs;        // 65536 each
  float* gsI = gsR + kB * kLs * kM;
  float* hsR = gsI + kB * kLs * kM;
  float* hsI = hsR + kB * kLs * kM;
  float* hdyn = hsI + kB * kLs * kM;  // 32768
  float* hstat = hdyn + kB * kHid;    // 131072
  float* mu_g = hstat + (size_t)kB * kM * kHid;  // 2048
  float* rs_g = mu_g + kM * kHid;                // 2048

  float* out = (float*)d_out;
  float* outSR = out;
  float* outSI = out + (size_t)kB * (kSteps + 1) * kLs;
  float* outRho = out + 2 * (size_t)kB * (kSteps + 1) * kLs;

  hipMemcpyAsync(phi, phi_in, (size_t)kB * kLs * sizeof(float),
                 hipMemcpyDeviceToDevice, stream);
  k_static<<<dim3(kB * 2), dim3(256), 0, stream>>>(w_real, w_imag, y, W1, b1, hstat);
  for (int step = 0; step < kSteps; ++step) {
    k_step_main<<<dim3(kB * kLs / 4 + kB * 2), dim3(256), 0, stream>>>(
        G_real, G_imag, H_real, H_imag, W1, phi, gsR, gsI, hsR, hsI, hdyn,
        outSR, outSI, step);
    k_bn<<<dim3(kM * kHid / 256), dim3(256), 0, stream>>>(hdyn, hstat, mu_g, rs_g);
    k_step_finish<<<dim3(kB), dim3(256), 0, stream>>>(
        gsR, gsI, hsR, hsI, hdyn, hstat, mu_g, rs_g, gamma_, beta_, W2, b2,
        phi, outRho, step);
  }
  k_final<<<dim3(kB), dim3(256), 0, stream>>>(phi, outSR, outSI);
}

// Round 3
// 707.508 us; speedup vs baseline: 1.1784x; 1.0110x over previous
//
#include <hip/hip_runtime.h>
#include <math.h>

typedef float f4 __attribute__((ext_vector_type(4)));

constexpr int kB = 64;
constexpr int kLs = 256;
constexpr int kM = 4;
constexpr int kLw = 256;
constexpr int kLy = 128;
constexpr int kHid = 512;
constexpr int kSteps = 6;
constexpr float kEps = 1e-5f;

__device__ __forceinline__ float wred(float v) {
#pragma unroll
  for (int off = 32; off > 0; off >>= 1) v += __shfl_down(v, off, 64);
  return v;
}

// h_static[b,m,hid] = b1[hid] + sum_l wy[b,m,l] * W1[512+l, hid]
__global__ __launch_bounds__(256) void k_static(
    const float* __restrict__ wr, const float* __restrict__ wi,
    const float* __restrict__ yy, const float* __restrict__ W1,
    const float* __restrict__ b1, float* __restrict__ hstat) {
  const int b = blockIdx.x >> 1;
  const int hid = ((blockIdx.x & 1) << 8) + threadIdx.x;
  const float* w1c = W1 + hid;
  f4 acc = {0.f, 0.f, 0.f, 0.f};
#pragma unroll 4
  for (int l = 0; l < kLw; ++l) {
    const float w1v = w1c[(size_t)(2 * kLs + l) * kHid];
    const f4 w = *(const f4*)(wr + ((size_t)b * kLw + l) * kM);
#pragma unroll
    for (int m = 0; m < kM; ++m) acc[m] += w[m] * w1v;
  }
#pragma unroll 4
  for (int l = 0; l < kLw; ++l) {
    const float w1v = w1c[(size_t)(2 * kLs + kLw + l) * kHid];
    const f4 w = *(const f4*)(wi + ((size_t)b * kLw + l) * kM);
#pragma unroll
    for (int m = 0; m < kM; ++m) acc[m] += w[m] * w1v;
  }
#pragma unroll 4
  for (int l = 0; l < kLy; ++l) {
    const float w1v = w1c[(size_t)(2 * kLs + 2 * kLw + l) * kHid];
    const f4 w = *(const f4*)(yy + ((size_t)b * kLy + l) * kM);
#pragma unroll
    for (int m = 0; m < kM; ++m) acc[m] += w[m] * w1v;
  }
  const float bv = b1[hid];
#pragma unroll
  for (int m = 0; m < kM; ++m)
    hstat[((size_t)b * kM + m) * kHid + hid] = acc[m] + bv;
}

// Per-step heavy kernel.
// Blocks 0..4095: matvec, one wave per (b,i) row. All 16 dwordx4 loads
//   (256 B/lane) are forced in flight before the first FMA via
//   sched_barrier(0); launch_bounds(256,1) lets the allocator keep the 64
//   load-result VGPRs live instead of serializing rounds at vmcnt(0).
// Blocks 4096..4223: h_dyn[b,hid].
__global__ __launch_bounds__(256, 1) void k_step_main(
    const float* __restrict__ Gr, const float* __restrict__ Gi,
    const float* __restrict__ Hr, const float* __restrict__ Hi,
    const float* __restrict__ W1, const float* __restrict__ phi,
    float* __restrict__ gsR, float* __restrict__ gsI,
    float* __restrict__ hsR, float* __restrict__ hsI,
    float* __restrict__ hdyn,
    float* __restrict__ outSR, float* __restrict__ outSI, int step) {
  __shared__ float sRe[kLs], sIm[kLs];
  const int t = threadIdx.x;
  const int blk = blockIdx.x;
  const int nMat = kB * kLs / 4;  // 4096
  const int b = (blk < nMat) ? (blk >> 6) : ((blk - nMat) >> 1);
  const float p = phi[b * kLs + t];
  float sn, cs;
  sincosf(p, &sn, &cs);
  sRe[t] = cs;
  sIm[t] = sn;
  __syncthreads();

  if (blk < nMat) {
    const int ic = blk & 63;
    if (ic == 0) {  // one block per b writes s outputs for this step
      const size_t oo = ((size_t)b * (kSteps + 1) + step) * kLs + t;
      outSR[oo] = cs;
      outSI[oo] = sn;
    }
    const int wv = t >> 6, lane = t & 63;
    const int i = (ic << 2) + wv;
    const size_t rowoff = ((size_t)b * kLs + i) * kLs * kM;
    const float* grp = Gr + rowoff + (size_t)lane * kM;
    const float* gip = Gi + rowoff + (size_t)lane * kM;
    const float* hrp = Hr + rowoff + (size_t)lane * kM;
    const float* hip_ = Hi + rowoff + (size_t)lane * kM;

    // ---- issue ALL 16 16-byte loads before any use ----
    f4 g_r[4], g_i[4], h_r[4], h_i[4];
#pragma unroll
    for (int r = 0; r < 4; ++r) {
      const size_t off = (size_t)(r << 6) * kM;
      g_r[r] = *(const f4*)(grp + off);
      g_i[r] = *(const f4*)(gip + off);
      h_r[r] = *(const f4*)(hrp + off);
      h_i[r] = *(const f4*)(hip_ + off);
    }
    // Hard fence for the instruction scheduler: nothing moves across.
    // Guarantees all 16 global_load_dwordx4 are issued before any consumer.
    __builtin_amdgcn_sched_barrier(0);

    f4 aGr = {0, 0, 0, 0}, aGi = {0, 0, 0, 0};
    f4 aHr = {0, 0, 0, 0}, aHi = {0, 0, 0, 0};
#pragma unroll
    for (int r = 0; r < 4; ++r) {
      const int j = (r << 6) + lane;
      const float sr = sRe[j], si = sIm[j];
#pragma unroll
      for (int m = 0; m < kM; ++m) {
        aGr[m] += g_r[r][m] * sr - g_i[r][m] * si;
        aGi[m] += g_r[r][m] * si + g_i[r][m] * sr;
        aHr[m] += h_r[r][m] * sr - h_i[r][m] * si;
        aHi[m] += h_r[r][m] * si + h_i[r][m] * sr;
      }
    }
#pragma unroll
    for (int m = 0; m < kM; ++m) {
      aGr[m] = wred(aGr[m]);
      aGi[m] = wred(aGi[m]);
      aHr[m] = wred(aHr[m]);
      aHi[m] = wred(aHi[m]);
    }
    if (lane == 0) {
      const size_t o = ((size_t)b * kLs + i) * kM;
      *(f4*)(gsR + o) = aGr;
      *(f4*)(gsI + o) = aGi;
      *(f4*)(hsR + o) = aHr;
      *(f4*)(hsI + o) = aHi;
    }
  } else {
    const int d = blk - nMat;
    const int hid = ((d & 1) << 8) + t;
    const float* w1c = W1 + hid;
    float acc = 0.f;
#pragma unroll 4
    for (int j = 0; j < kLs; ++j) {
      acc += sRe[j] * w1c[(size_t)j * kHid];
      acc += sIm[j] * w1c[(size_t)(j + kLs) * kHid];
    }
    hdyn[b * kHid + hid] = acc;
  }
}

// BN batch stats over b for each (m,hid). grid: 8 blocks x 256 threads.
__global__ __launch_bounds__(256) void k_bn(
    const float* __restrict__ hdyn, const float* __restrict__ hstat,
    float* __restrict__ mu_g, float* __restrict__ rs_g) {
  const int q = blockIdx.x * 256 + threadIdx.x;  // 0..2047
  const int m = q >> 9;
  const int hid = q & (kHid - 1);
  float sum = 0.f, ss = 0.f;
#pragma unroll 8
  for (int bb = 0; bb < kB; ++bb) {
    const float h = hdyn[bb * kHid + hid] + hstat[((size_t)bb * kM + m) * kHid + hid];
    sum += h;
    ss += h * h;
  }
  const float mu = sum * (1.f / kB);
  const float var = ss * (1.f / kB) - mu * mu;
  mu_g[q] = mu;
  rs_g[q] = rsqrtf(var + kEps);
}

// Per-step tail: one block per b. sGs/sHs, rho, eta_net, phi update.
__global__ __launch_bounds__(256) void k_step_finish(
    const float* __restrict__ gsR, const float* __restrict__ gsI,
    const float* __restrict__ hsR, const float* __restrict__ hsI,
    const float* __restrict__ hdyn, const float* __restrict__ hstat,
    const float* __restrict__ mu_g, const float* __restrict__ rs_g,
    const float* __restrict__ gamma_, const float* __restrict__ beta_,
    const float* __restrict__ W2, const float* __restrict__ b2,
    float* __restrict__ phi, float* __restrict__ outRho, int step) {
  const int b = blockIdx.x, t = threadIdx.x;
  const int lane = t & 63, wv = t >> 6;
  __shared__ float red[4][16];
  __shared__ float sgR[4], sgI[4], shR[4], shI[4], c2[4];
  __shared__ float rho_s[4];

  const float p = phi[b * kLs + t];
  float sn, cs;
  sincosf(p, &sn, &cs);

  const size_t o = ((size_t)b * kLs + t) * kM;
  const f4 gR = *(const f4*)(gsR + o);
  const f4 gI = *(const f4*)(gsI + o);
  const f4 hR = *(const f4*)(hsR + o);
  const f4 hI = *(const f4*)(hsI + o);

  // partials of sGs = sum_i conj(s_i)*Gs[i], sHs likewise
  float v[16];
#pragma unroll
  for (int m = 0; m < kM; ++m) {
    v[m] = cs * gR[m] + sn * gI[m];       // Re(conj(s)*Gs)
    v[4 + m] = cs * gI[m] - sn * gR[m];   // Im(conj(s)*Gs)
    v[8 + m] = cs * hR[m] + sn * hI[m];
    v[12 + m] = cs * hI[m] - sn * hR[m];
  }
#pragma unroll
  for (int k = 0; k < 16; ++k) v[k] = wred(v[k]);
  if (lane == 0) {
#pragma unroll
    for (int k = 0; k < 16; ++k) red[wv][k] = v[k];
  }
  __syncthreads();
  if (t == 0) {
#pragma unroll
    for (int m = 0; m < kM; ++m) {
      const float gr = red[0][m] + red[1][m] + red[2][m] + red[3][m];
      const float gi = red[0][4 + m] + red[1][4 + m] + red[2][4 + m] + red[3][4 + m];
      const float hr = red[0][8 + m] + red[1][8 + m] + red[2][8 + m] + red[3][8 + m];
      const float hi = red[0][12 + m] + red[1][12 + m] + red[2][12 + m] + red[3][12 + m];
      sgR[m] = gr; sgI[m] = gi; shR[m] = hr; shI[m] = hi;
      const float xr = hr * hr - hi * hi;   // Re(sHs^2)
      const float xi = 2.f * hr * hi;       // Im(sHs^2)
      c2[m] = 2.f * xr / (xr * xr + xi * xi);  // Re(2/sHs^2)
    }
  }
  __syncthreads();

  // rho[b,m] = sigmoid( relu(bn(h)) . W2 + b2 )
  float pm[4] = {0.f, 0.f, 0.f, 0.f};
#pragma unroll
  for (int kk = 0; kk < 2; ++kk) {
    const int hid = (kk << 8) + t;
    const float hd = hdyn[b * kHid + hid];
    const float ga = gamma_[hid], be = beta_[hid], w2 = W2[hid];
#pragma unroll
    for (int m = 0; m < kM; ++m) {
      const float h = hd + hstat[((size_t)b * kM + m) * kHid + hid];
      const int q = m * kHid + hid;
      float hn = ga * (h - mu_g[q]) * rs_g[q] + be;
      hn = fmaxf(hn, 0.f);
      pm[m] += hn * w2;
    }
  }
#pragma unroll
  for (int m = 0; m < kM; ++m) pm[m] = wred(pm[m]);
  if (lane == 0) {
#pragma unroll
    for (int m = 0; m < kM; ++m) red[wv][m] = pm[m];
  }
  __syncthreads();
  if (t < 4) {
    const float tot = red[0][t] + red[1][t] + red[2][t] + red[3][t] + b2[0];
    const float r = 1.f / (1.f + expf(-tot));
    rho_s[t] = r;
    outRho[((size_t)b * kSteps + step) * kM + t] = r;
  }
  __syncthreads();

  // eta_net[b,i=t] = sum_m c2[m] * Im((sHs*Gs - sGs*Hs)*conj(s_i)) * rho[m]
  float en = 0.f;
#pragma unroll
  for (int m = 0; m < kM; ++m) {
    const float ar = shR[m] * gR[m] - shI[m] * gI[m] - (sgR[m] * hR[m] - sgI[m] * hI[m]);
    const float ai = shR[m] * gI[m] + shI[m] * gR[m] - (sgR[m] * hI[m] + sgI[m] * hR[m]);
    en += c2[m] * (ai * cs - ar * sn) * rho_s[m];
  }
  phi[b * kLs + t] = p - en;
}

__global__ __launch_bounds__(256) void k_final(const float* __restrict__ phi,
                                               float* __restrict__ outSR,
                                               float* __restrict__ outSI) {
  const int b = blockIdx.x, t = threadIdx.x;
  float sn, cs;
  sincosf(phi[b * kLs + t], &sn, &cs);
  const size_t oo = ((size_t)b * (kSteps + 1) + kSteps) * kLs + t;
  outSR[oo] = cs;
  outSI[oo] = sn;
}

extern "C" void kernel_launch(void* const* d_in, const int* in_sizes, int n_in,
                              void* d_out, int out_size, void* d_ws, size_t ws_size,
                              hipStream_t stream) {
  const float* phi_in = (const float*)d_in[0];
  const float* w_real = (const float*)d_in[1];
  const float* w_imag = (const float*)d_in[2];
  const float* y = (const float*)d_in[3];
  const float* G_real = (const float*)d_in[4];
  const float* G_imag = (const float*)d_in[5];
  const float* H_real = (const float*)d_in[6];
  const float* H_imag = (const float*)d_in[7];
  const float* W1 = (const float*)d_in[8];
  const float* b1 = (const float*)d_in[9];
  const float* gamma_ = (const float*)d_in[10];
  const float* beta_ = (const float*)d_in[11];
  const float* W2 = (const float*)d_in[12];
  const float* b2 = (const float*)d_in[13];

  float* ws = (float*)d_ws;
  float* phi = ws;                    // 16384
  float* gsR = phi + kB * kLs;        // 65536 each
  float* gsI = gsR + kB * kLs * kM;
  float* hsR = gsI + kB * kLs * kM;
  float* hsI = hsR + kB * kLs * kM;
  float* hdyn = hsI + kB * kLs * kM;  // 32768
  float* hstat = hdyn + kB * kHid;    // 131072
  float* mu_g = hstat + (size_t)kB * kM * kHid;  // 2048
  float* rs_g = mu_g + kM * kHid;                // 2048

  float* out = (float*)d_out;
  float* outSR = out;
  float* outSI = out + (size_t)kB * (kSteps + 1) * kLs;
  float* outRho = out + 2 * (size_t)kB * (kSteps + 1) * kLs;

  hipMemcpyAsync(phi, phi_in, (size_t)kB * kLs * sizeof(float),
                 hipMemcpyDeviceToDevice, stream);
  k_static<<<dim3(kB * 2), dim3(256), 0, stream>>>(w_real, w_imag, y, W1, b1, hstat);
  for (int step = 0; step < kSteps; ++step) {
    k_step_main<<<dim3(kB * kLs / 4 + kB * 2), dim3(256), 0, stream>>>(
        G_real, G_imag, H_real, H_imag, W1, phi, gsR, gsI, hsR, hsI, hdyn,
        outSR, outSI, step);
    k_bn<<<dim3(kM * kHid / 256), dim3(256), 0, stream>>>(hdyn, hstat, mu_g, rs_g);
    k_step_finish<<<dim3(kB), dim3(256), 0, stream>>>(
        gsR, gsI, hsR, hsI, hdyn, hstat, mu_g, rs_g, gamma_, beta_, W2, b2,
        phi, outRho, step);
  }
  k_final<<<dim3(kB), dim3(256), 0, stream>>>(phi, outSR, outSI);
}